// Round 12
// baseline (126.075 us; speedup 1.0000x reference)
//
#include <hip/hip_runtime.h>

#define NQ   12
#define DIM  4096
#define NL   4
#define BLK  256
#define IMOFF 16384

typedef unsigned short u16;
typedef unsigned int   u32;
typedef float f2 __attribute__((ext_vector_type(2)));

// ---------- compile-time GF(2) linear algebra for the CNOT-chain permutation ----------
struct L12 { u16 b[NQ]; };

static constexpr int pcnt(u32 v){ return __builtin_popcount(v); }
static constexpr u32 lap(const L12& A, u32 x){ u32 r=0; for(int p=0;p<NQ;++p) if((x>>p)&1u) r^=A.b[p]; return r; }
static constexpr L12 lcomp(const L12& A, const L12& B){ L12 r{}; for(int p=0;p<NQ;++p) r.b[p]=(u16)lap(A,(u32)B.b[p]); return r; }
static constexpr L12 lident(){ L12 r{}; for(int p=0;p<NQ;++p) r.b[p]=(u16)(1u<<p); return r; }

static constexpr u32 applyT(u32 i){
  i ^= ((i>>0)&1u) << 11;                            // CNOT(11,0): bit11 ^= bit0
  for(int q=10;q>=0;--q){ int pc2=11-q, pt=10-q; i ^= ((i>>pc2)&1u) << pt; }
  return i;
}
static constexpr L12 lT(){ L12 t{}; for(int p=0;p<NQ;++p) t.b[p]=(u16)applyT(1u<<p); return t; }

static constexpr L12 linv(const L12& A){              // GF(2) Gauss-Jordan
  u16 v[NQ]={}; u16 u[NQ]={};
  for(int p=0;p<NQ;++p){ v[p]=A.b[p]; u[p]=(u16)(1u<<p); }
  for(int t=0;t<NQ;++t){
    int p=t; while(!((v[p]>>t)&1u)) ++p;
    u16 tv=v[p]; v[p]=v[t]; v[t]=tv; u16 tu=u[p]; u[p]=u[t]; u[t]=tu;
    for(int k=0;k<NQ;++k) if(k!=t && ((v[k]>>t)&1u)){ v[k]^=v[t]; u[k]^=u[t]; }
  }
  L12 r{}; for(int p=0;p<NQ;++p) r.b[p]=u[p]; return r;
}
static constexpr L12 ltr(const L12& A){
  L12 r{}; for(int p=0;p<NQ;++p) for(int q=0;q<NQ;++q) if((A.b[p]>>q)&1u) r.b[q]=(u16)(r.b[q]|(1u<<p));
  return r;
}

struct Tables {
  u16 cm[12][16];   // [step][combo] xor-offsets spanning the 4 gate masks
  u16 wg[12][4];    // [step][gate] parity mask: a0/a1 role selector
  u16 sp[12][4];    // [step] sorted pivot bit positions
  u16 wexp[NQ];     // final <Z> parity masks: rows of (T^4)^{-T}
};

static constexpr Tables make_tables(){
  Tables tb{};
  const L12 T   = lT();
  const L12 Tit = ltr(linv(T));   // T^{-T}
  L12 A = lident();               // A_l = T^l   (stored_index = A_l(true_index))
  L12 W = lident();               // W_l = A_l^{-T}
  for(int l=0;l<NL;++l){
    for(int g=0;g<3;++g){
      const int st = l*3+g;
      u16 mm[4]={0,0,0,0};
      for(int i=0;i<4;++i){ mm[i]=A.b[4*g+i]; tb.wg[st][i]=W.b[4*g+i]; }
      u32 ech[4]={0,0,0,0}; int piv[4]={0,0,0,0};
      for(int i=0;i<4;++i){
        u32 v=mm[i];
        for(int k=0;k<i;++k) if((v>>piv[k])&1u) v^=ech[k];
        int t2=11; while(!((v>>t2)&1u)) --t2;
        piv[i]=t2; ech[i]=v;
      }
      for(int a2=0;a2<4;++a2) for(int b2=a2+1;b2<4;++b2)
        if(piv[b2]<piv[a2]){ int tt=piv[a2]; piv[a2]=piv[b2]; piv[b2]=tt; }
      for(int i=0;i<4;++i) tb.sp[st][i]=(u16)piv[i];
      for(int c=0;c<16;++c){ u32 m=0; for(int i=0;i<4;++i) if((c>>i)&1) m^=mm[i]; tb.cm[st][c]=(u16)m; }
    }
    A = lcomp(A, T);
    W = lcomp(W, Tit);
  }
  for(int p=0;p<NQ;++p) tb.wexp[p]=W.b[p];
  return tb;
}

__device__ constexpr Tables TB = make_tables();

// ---------- LDS swizzle: slot = j ^ fold(j>>4), fold linear over GF(2) ----------
static constexpr u16 UIMG[12] = {1,2,4,8, 3,5,6,7, 9,10,11,13};

static constexpr u32 swz(u32 j){
  u32 f=0;
  for(int k=4;k<12;++k) if((j>>k)&1u) f ^= (u32)UIMG[k];
  return j ^ (f & 15u);
}

struct Derived {
  u32 lane_c[12][8];  // tid bit k -> (swz(1<<pos)<<2) | (role-parity nibble <<28)
  u32 smb[12][4];     // swz(cm[1<<i])<<2  (rep parity correction, swizzled)
  u32 scmb[12][16];   // swz(cm[c])<<2     (coset member byte offsets, re-plane)
  u32 g0lane[8];      // step 0: unswizzled element-index contribution of tid bit k
  u32 u11lane[8];     // step 11: unswizzled index contribution of tid bit k
  u32 u11smb[4];      // step 11: unswizzled cm[1<<i]
  u16 pm[12];         // wexp[11-q]: per-thread parity mask on unswizzled rep
  u16 mu[12];         // Walsh index per output q
};

static constexpr Derived make_derived(){
  const Tables tb = make_tables();
  Derived d{};
  for(int st=0; st<12; ++st){
    bool isp[12]={false,false,false,false,false,false,false,false,false,false,false,false};
    for(int i=0;i<4;++i) isp[tb.sp[st][i]]=true;
    int np[8]={}; int nn=0;
    for(int p=0;p<12;++p) if(!isp[p]) np[nn++]=p;
    // b32 bank model: 32 banks, bank = slot bits 0-4. Lane bits 0-3 need
    // fold-image (bits 0-3) rank 4; lane bit 4 should carry bank bit 4 --
    // only index-position 4 maps there (fold touches bits 0-3 only).
    int s4=-1;
    for(int j=0;j<8;++j) if(np[j]==4) s4=j;
    int bestmask=-1;
    for(int avoid=1; avoid>=0 && bestmask<0; --avoid){
      for(int ms=0; ms<256 && bestmask<0; ++ms){
        if(pcnt((u32)ms)!=4) continue;
        if(avoid==1 && s4>=0 && ((ms>>s4)&1)) continue;   // keep pos-4 free for lane bit 4
        u16 bas[4]={0,0,0,0}; int rk=0;
        for(int k=0;k<8;++k){
          if(!((ms>>k)&1)) continue;
          u16 x=(u16)(swz(1u<<np[k])&15u);
          while(x){
            int hbx=3; while(hbx>0 && !((x>>hbx)&1)) --hbx;
            if(bas[hbx]) x=(u16)(x^bas[hbx]);
            else { bas[hbx]=x; ++rk; x=0; }
          }
        }
        if(rk==4) bestmask=ms;
      }
    }
    if(bestmask<0) bestmask=0x0F;
    bool used[8]={};
    int pos[8]={}; int lo=0;
    for(int k=0;k<8;++k) if((bestmask>>k)&1){ pos[lo++]=np[k]; used[k]=true; }
    if(s4>=0 && !used[s4]){ pos[lo++]=np[s4]; used[s4]=true; }   // lane bit 4 = index bit 4
    for(int k=0;k<8;++k) if(!used[k]){ pos[lo++]=np[k]; }
    for(int k=0;k<8;++k){
      const u32 addr = swz(1u<<pos[k])<<2;
      u32 nib=0;
      for(int i=0;i<4;++i) nib |= (u32)((tb.wg[st][i]>>pos[k])&1u)<<i;
      d.lane_c[st][k] = addr | (nib<<28);
      if(st==0)  d.g0lane[k]  = 1u<<pos[k];
      if(st==11) d.u11lane[k] = 1u<<pos[k];
    }
    for(int i=0;i<4;++i)  d.smb[st][i]  = swz((u32)tb.cm[st][1<<i])<<2;
    for(int c=0;c<16;++c) d.scmb[st][c] = swz((u32)tb.cm[st][c])<<2;
    if(st==11) for(int i=0;i<4;++i) d.u11smb[i] = (u32)tb.cm[11][1<<i];
  }
  for(int q=0;q<12;++q){
    d.pm[q] = tb.wexp[11-q];
    u32 m=0;
    for(int i=0;i<4;++i) m |= (u32)(pcnt((u32)tb.cm[11][1u<<i] & (u32)tb.wexp[11-q])&1)<<i;
    d.mu[q]=(u16)m;
  }
  return d;
}

__device__ constexpr Derived DV = make_derived();

// ---------- 4 commuting gates via 3-shear rotations (proven R4 form) ----------
// gw[g] = {tan(ty/4), sin(ty/2), tan(tz/2), sin(tz)}  (global phase dropped)
template<int ST, bool WITHW>
__device__ __forceinline__ void gates(f2 (&a)[16], const float4* __restrict__ gw){
#pragma unroll
  for(int i=0;i<4;++i){
    const float4 g = gw[ST*4+i];
    const f2 mt = {-g.x, -g.x};
    const f2 sy = { g.y,  g.y};
#pragma unroll
    for(int c=0;c<16;++c){
      if((c>>i)&1) continue;
      const int c1 = c|(1<<i);
      f2 u = __builtin_elementwise_fma(mt, a[c1], a[c]);   // u  = a0 - t*a1
      f2 v = __builtin_elementwise_fma(sy, u, a[c1]);      // a1'= a1 + s*u
      a[c] = __builtin_elementwise_fma(mt, v, u);          // a0'= u  - t*a1'
      if(WITHW){                                           // rotate (v.x,v.y) by +tz
        const float t = fmaf(-g.z, v.y, v.x);
        v.y = fmaf( g.w, t, v.y);
        v.x = fmaf(-g.z, v.y, t);
      }
      a[c1]=v;
    }
  }
}

template<int ST, bool WITHW>
__device__ __forceinline__ void mid_step(const u32* msk, char* lds, const float4* __restrict__ gw){
  u32 acc=0;
#pragma unroll
  for(int k=0;k<8;++k) acc ^= DV.lane_c[ST][k]&msk[k];
  const u32 nib = acc>>28;
  u32 base = acc & 0x0FFFFFFFu;
#pragma unroll
  for(int i=0;i<4;++i) base ^= DV.smb[ST][i] & (0u-((nib>>i)&1u));
  u32 ad[16]; f2 a[16];
#pragma unroll
  for(int c=0;c<16;++c){
    ad[c] = base ^ DV.scmb[ST][c];
    a[c].x = *(const float*)(lds+ad[c]);
    a[c].y = *(const float*)(lds+ad[c]+IMOFF);
  }
  gates<ST,WITHW>(a,gw);
#pragma unroll
  for(int c=0;c<16;++c){
    *(float*)(lds+ad[c])       = a[c].x;
    *(float*)(lds+ad[c]+IMOFF) = a[c].y;
  }
  __syncthreads();
}

__global__ void prep_kernel(const float* __restrict__ w, float4* __restrict__ gw){
  const int t = threadIdx.x;
  if(t < NL*NQ){
    const int l=t/NQ, p=t%NQ, q=(NQ-1)-p;
    const float ty=w[(l*NQ+q)*2+0], tz=w[(l*NQ+q)*2+1];
    gw[t]=make_float4(tanf(0.25f*ty), sinf(0.5f*ty), tanf(0.5f*tz), sinf(tz));
  }
}

__global__ __launch_bounds__(BLK, 5) void qsim_kernel(const float* __restrict__ x,
                                                      const float4* __restrict__ gw,
                                                      float* __restrict__ out)
{
  __shared__ float st2[2*DIM];         // re-plane [0,16K), im-plane [16K,32K)
  char* lds = (char*)st2;
  const int tid = threadIdx.x;
  const int bb  = blockIdx.x;

  u32 msk[8];
#pragma unroll
  for(int k=0;k<8;++k) msk[k]=0u-((u32)(tid>>k)&1u);

  // ---- step 0: masks are bits 0..3 -> coset = 16 consecutive floats in global ----
  u32 rep0=0, acc0=0;
#pragma unroll
  for(int k=0;k<8;++k){ rep0 ^= DV.g0lane[k]&msk[k]; acc0 ^= DV.lane_c[0][k]&msk[k]; }
  const u32 base0 = acc0 & 0x0FFFFFFFu;   // nib == 0 at step 0

  f2 a[16];
  const float* xr = x + (size_t)bb*DIM + rep0;
#pragma unroll
  for(int s=0;s<4;++s){
    const float4 v = *reinterpret_cast<const float4*>(xr + 4*s);
    a[4*s+0]=(f2){v.x,0.f}; a[4*s+1]=(f2){v.y,0.f};
    a[4*s+2]=(f2){v.z,0.f}; a[4*s+3]=(f2){v.w,0.f};
  }
  gates<0,true>(a,gw);
#pragma unroll
  for(int c=0;c<16;++c){
    const u32 ad = base0 ^ DV.scmb[0][c];
    *(float*)(lds+ad)       = a[c].x;
    *(float*)(lds+ad+IMOFF) = a[c].y;
  }
  __syncthreads();

  // ---- steps 1..10: LDS round trips ----
  mid_step<1,true >(msk,lds,gw);
  mid_step<2,true >(msk,lds,gw);
  mid_step<3,true >(msk,lds,gw);
  mid_step<4,true >(msk,lds,gw);
  mid_step<5,true >(msk,lds,gw);
  mid_step<6,true >(msk,lds,gw);
  mid_step<7,true >(msk,lds,gw);
  mid_step<8,true >(msk,lds,gw);
  mid_step<9,false>(msk,lds,gw);     // last layer: RZ phase dropped (|amp|^2 readout)
  mid_step<10,false>(msk,lds,gw);

  // ---- step 11 + fused Walsh readout (no write-back) ----
  {
    u32 acc=0, urep=0;
#pragma unroll
    for(int k=0;k<8;++k){ acc ^= DV.lane_c[11][k]&msk[k]; urep ^= DV.u11lane[k]&msk[k]; }
    const u32 nib = acc>>28;
    u32 base = acc & 0x0FFFFFFFu;
#pragma unroll
    for(int i=0;i<4;++i){ const u32 mi=0u-((nib>>i)&1u); base ^= DV.smb[11][i]&mi; urep ^= DV.u11smb[i]&mi; }
#pragma unroll
    for(int c=0;c<16;++c){
      const u32 ad = base ^ DV.scmb[11][c];
      a[c].x = *(const float*)(lds+ad);
      a[c].y = *(const float*)(lds+ad+IMOFF);
    }
    gates<11,false>(a,gw);

    float pr[16];
#pragma unroll
    for(int c=0;c<16;++c) pr[c]=fmaf(a[c].x,a[c].x, a[c].y*a[c].y);
    // Walsh-Hadamard over the 4 combo bits: W[m] = sum_c (-1)^{popc(c&m)} pr[c]
#pragma unroll
    for(int b=1;b<16;b<<=1){
#pragma unroll
      for(int c=0;c<16;++c){
        if(c&b) continue;
        const float u=pr[c], v=pr[c|b];
        pr[c]=u+v; pr[c|b]=u-v;
      }
    }
    float accq[12];
#pragma unroll
    for(int q=0;q<12;++q){
      const u32 sb = ((u32)__popc(urep & (u32)DV.pm[q]) & 1u)<<31;
      accq[q]=__uint_as_float(__float_as_uint(pr[DV.mu[q]])^sb);
    }
    float nrm2 = pr[0];
#pragma unroll
    for(int o=32;o;o>>=1){
      nrm2 += __shfl_xor(nrm2,o);
#pragma unroll
      for(int q=0;q<12;++q) accq[q]+=__shfl_xor(accq[q],o);
    }
    __syncthreads();                      // all waves done reading step 11
    float* wredf = (float*)lds;           // alias reduction buffer into state LDS
    const int wid=tid>>6;
    if((tid&63)==0){
#pragma unroll
      for(int q=0;q<12;++q) wredf[wid*13+q]=accq[q];
      wredf[wid*13+12]=nrm2;
    }
    __syncthreads();
    if(tid<NQ){
      const float s0=wredf[0*13+tid]+wredf[1*13+tid]+wredf[2*13+tid]+wredf[3*13+tid];
      const float sn=wredf[0*13+12]+wredf[1*13+12]+wredf[2*13+12]+wredf[3*13+12];
      out[(size_t)bb*NQ+tid]=s0/sn;
    }
  }
}

extern "C" void kernel_launch(void* const* d_in, const int* in_sizes, int n_in,
                              void* d_out, int out_size, void* d_ws, size_t ws_size,
                              hipStream_t stream) {
  const float* x = (const float*)d_in[0];
  const float* w = (const float*)d_in[1];
  float* out = (float*)d_out;
  float4* gw = (float4*)d_ws;
  const int B = in_sizes[0] / DIM;
  prep_kernel<<<1, 64, 0, stream>>>(w, gw);
  qsim_kernel<<<B, BLK, 0, stream>>>(x, gw, out);
}

// Round 13
// 105.941 us; speedup vs baseline: 1.1900x; 1.1900x over previous
//
#include <hip/hip_runtime.h>

#define NQ   12
#define DIM  4096
#define NL   4
#define BLK  256

typedef unsigned short u16;
typedef unsigned int   u32;
typedef float f2 __attribute__((ext_vector_type(2)));

// ---------- compile-time GF(2) linear algebra for the CNOT-chain permutation ----------
struct L12 { u16 b[NQ]; };

static constexpr u32 lap(const L12& A, u32 x){ u32 r=0; for(int p=0;p<NQ;++p) if((x>>p)&1u) r^=A.b[p]; return r; }
static constexpr L12 lcomp(const L12& A, const L12& B){ L12 r{}; for(int p=0;p<NQ;++p) r.b[p]=(u16)lap(A,(u32)B.b[p]); return r; }
static constexpr L12 lident(){ L12 r{}; for(int p=0;p<NQ;++p) r.b[p]=(u16)(1u<<p); return r; }

static constexpr u32 applyT(u32 i){
  i ^= ((i>>0)&1u) << 11;                            // CNOT(11,0): bit11 ^= bit0
  for(int q=10;q>=0;--q){ int pc=11-q, pt=10-q; i ^= ((i>>pc)&1u) << pt; }
  return i;
}
static constexpr L12 lT(){ L12 t{}; for(int p=0;p<NQ;++p) t.b[p]=(u16)applyT(1u<<p); return t; }

static constexpr L12 linv(const L12& A){              // GF(2) Gauss-Jordan
  u16 v[NQ]={}; u16 u[NQ]={};
  for(int p=0;p<NQ;++p){ v[p]=A.b[p]; u[p]=(u16)(1u<<p); }
  for(int t=0;t<NQ;++t){
    int p=t; while(!((v[p]>>t)&1u)) ++p;
    u16 tv=v[p]; v[p]=v[t]; v[t]=tv; u16 tu=u[p]; u[p]=u[t]; u[t]=tu;
    for(int k=0;k<NQ;++k) if(k!=t && ((v[k]>>t)&1u)){ v[k]^=v[t]; u[k]^=u[t]; }
  }
  L12 r{}; for(int p=0;p<NQ;++p) r.b[p]=u[p]; return r;
}
static constexpr L12 ltr(const L12& A){
  L12 r{}; for(int p=0;p<NQ;++p) for(int q=0;q<NQ;++q) if((A.b[p]>>q)&1u) r.b[q]=(u16)(r.b[q]|(1u<<p));
  return r;
}
static constexpr int cpop(u32 v){ int n=0; while(v){ n+=(int)(v&1u); v>>=1; } return n; }

struct Tables {
  u16 cm[12][16];   // [step][combo] xor-offsets spanning the 4 gate masks
  u16 wg[12][4];    // [step][gate] parity mask: a0/a1 role selector
  u16 sp[12][4];    // [step] sorted pivot bit positions
  u16 wexp[NQ];     // final <Z> parity masks: rows of (T^4)^{-T}
};

static constexpr Tables make_tables(){
  Tables tb{};
  const L12 T   = lT();
  const L12 Tit = ltr(linv(T));   // T^{-T}
  L12 A = lident();               // A_l = T^l   (stored_index = A_l(true_index))
  L12 W = lident();               // W_l = A_l^{-T}
  for(int l=0;l<NL;++l){
    for(int g=0;g<3;++g){
      const int st = l*3+g;
      u16 mm[4]={0,0,0,0};
      for(int i=0;i<4;++i){ mm[i]=A.b[4*g+i]; tb.wg[st][i]=W.b[4*g+i]; }
      u32 ech[4]={0,0,0,0}; int piv[4]={0,0,0,0};
      for(int i=0;i<4;++i){
        u32 v=mm[i];
        for(int k=0;k<i;++k) if((v>>piv[k])&1u) v^=ech[k];
        int t2=11; while(!((v>>t2)&1u)) --t2;
        piv[i]=t2; ech[i]=v;
      }
      for(int a2=0;a2<4;++a2) for(int b2=a2+1;b2<4;++b2)
        if(piv[b2]<piv[a2]){ int tt=piv[a2]; piv[a2]=piv[b2]; piv[b2]=tt; }
      for(int i=0;i<4;++i) tb.sp[st][i]=(u16)piv[i];
      for(int c=0;c<16;++c){ u32 m=0; for(int i=0;i<4;++i) if((c>>i)&1) m^=mm[i]; tb.cm[st][c]=(u16)m; }
    }
    A = lcomp(A, T);
    W = lcomp(W, Tit);
  }
  for(int p=0;p<NQ;++p) tb.wexp[p]=W.b[p];
  return tb;
}

__device__ constexpr Tables TB = make_tables();

// ---------- LDS swizzle: slot = j ^ fold(j>>4), fold linear over GF(2) ----------
static constexpr u16 UIMG[12] = {1,2,4,8, 3,5,6,7, 9,10,11,13};

static constexpr u32 swz(u32 j){
  u32 f=0;
  for(int k=4;k<12;++k) if((j>>k)&1u) f ^= (u32)UIMG[k];
  return j ^ (f & 15u);
}

struct Derived {
  u32 lane_c[12][8];  // tid bit k -> (swz(1<<pos)<<3) | (role-parity nibble <<28)
  u32 smb[12][4];     // swz(cm[1<<i])<<3  (rep parity correction, swizzled)
  u32 scmb[12][16];   // swz(cm[c])<<3     (coset member byte offsets)
  u32 g0lane[8];      // step 0: unswizzled element-index contribution of tid bit k
  u32 u11lane[8];     // step 11: unswizzled index contribution of tid bit k
  u32 u11smb[4];      // step 11: unswizzled cm[1<<i]
  u16 pm[12];         // wexp[11-q]: per-thread parity mask on unswizzled rep
  u16 mu[12];         // Walsh index per output q
};

static constexpr Derived make_derived(){
  const Tables tb = make_tables();
  Derived d{};
  for(int st=0; st<12; ++st){
    bool isp[12]={false,false,false,false,false,false,false,false,false,false,false,false};
    for(int i=0;i<4;++i) isp[tb.sp[st][i]]=true;
    int np[8]={}; int nn=0;
    for(int p=0;p<12;++p) if(!isp[p]) np[nn++]=p;
    // choose 6 of 8 non-pivot positions for lane bits s.t. their GF(2)^4
    // bank-pair images have rank 4 -> exactly 4 lanes/bank-pair (b64 floor)
    int best=-1;
    for(int ms=0; ms<256; ++ms){
      int pc=0; for(int k=0;k<8;++k) pc+=(ms>>k)&1;
      if(pc!=6) continue;
      u16 bas[4]={0,0,0,0}; int r=0;
      for(int k=0;k<8;++k){
        if(!((ms>>k)&1)) continue;
        u16 x=(u16)(UIMG[np[k]]&15);
        while(x){
          int hb=3; while(!((x>>hb)&1)) --hb;
          if(bas[hb]) x=(u16)(x^bas[hb]);
          else { bas[hb]=x; ++r; x=0; }
        }
      }
      if(r==4){ best=ms; break; }
    }
    if(best<0) best=0x3F;
    int pos[8]={}; int lo=0, hi=6;
    for(int k=0;k<8;++k){ if((best>>k)&1) pos[lo++]=np[k]; else pos[hi++]=np[k]; }
    for(int k=0;k<8;++k){
      const u32 addr = swz(1u<<pos[k])<<3;
      u32 nib=0;
      for(int i=0;i<4;++i) nib |= (u32)((tb.wg[st][i]>>pos[k])&1u)<<i;
      d.lane_c[st][k] = addr | (nib<<28);
      if(st==0)  d.g0lane[k]  = 1u<<pos[k];
      if(st==11) d.u11lane[k] = 1u<<pos[k];
    }
    for(int i=0;i<4;++i)  d.smb[st][i]  = swz((u32)tb.cm[st][1<<i])<<3;
    for(int c=0;c<16;++c) d.scmb[st][c] = swz((u32)tb.cm[st][c])<<3;
    if(st==11) for(int i=0;i<4;++i) d.u11smb[i] = (u32)tb.cm[11][1<<i];
  }
  for(int q=0;q<12;++q){
    d.pm[q] = tb.wexp[11-q];
    u32 m=0;
    for(int i=0;i<4;++i) m |= (u32)(cpop((u32)tb.cm[11][1u<<i] & (u32)tb.wexp[11-q])&1)<<i;
    d.mu[q]=(u16)m;
  }
  return d;
}

__device__ constexpr Derived DV = make_derived();

// ---------- 4 commuting gates via 3-shear rotations (all-FMA) ----------
// gw[g] = {tan(ty/4), sin(ty/2), tan(tz/2), sin(tz)}  (global phase dropped)
template<int ST, bool WITHW>
__device__ __forceinline__ void gates(f2 (&a)[16], const float4* __restrict__ gw){
#pragma unroll
  for(int i=0;i<4;++i){
    const float4 g = gw[ST*4+i];
    const f2 mt = {-g.x, -g.x};
    const f2 sy = { g.y,  g.y};
#pragma unroll
    for(int c=0;c<16;++c){
      if((c>>i)&1) continue;
      const int c1 = c|(1<<i);
      f2 u = __builtin_elementwise_fma(mt, a[c1], a[c]);   // u  = a0 - t*a1
      f2 v = __builtin_elementwise_fma(sy, u, a[c1]);      // a1'= a1 + s*u
      a[c] = __builtin_elementwise_fma(mt, v, u);          // a0'= u  - t*a1'
      if(WITHW){                                           // rotate (v.x,v.y) by +tz
        const float t = fmaf(-g.z, v.y, v.x);
        v.y = fmaf( g.w, t, v.y);
        v.x = fmaf(-g.z, v.y, t);
      }
      a[c1]=v;
    }
  }
}

template<int ST, bool WITHW>
__device__ __forceinline__ void mid_step(const u32* msk, char* lds, const float4* __restrict__ gw){
  u32 acc=0;
#pragma unroll
  for(int k=0;k<8;++k) acc ^= DV.lane_c[ST][k]&msk[k];
  const u32 nib = acc>>28;
  u32 base = acc & 0x0FFFFFFFu;
#pragma unroll
  for(int i=0;i<4;++i) base ^= DV.smb[ST][i] & (0u-((nib>>i)&1u));
  u32 ad[16]; f2 a[16];
#pragma unroll
  for(int c=0;c<16;++c){
    ad[c] = base ^ DV.scmb[ST][c];
    a[c] = *(const f2*)(lds+ad[c]);
  }
  gates<ST,WITHW>(a,gw);
#pragma unroll
  for(int c=0;c<16;++c){ *(f2*)(lds+ad[c]) = a[c]; }
  __syncthreads();
}

__global__ void prep_kernel(const float* __restrict__ w, float4* __restrict__ gw){
  const int t = threadIdx.x;
  if(t < NL*NQ){
    const int l=t/NQ, p=t%NQ, q=(NQ-1)-p;
    const float ty=w[(l*NQ+q)*2+0], tz=w[(l*NQ+q)*2+1];
    gw[t]=make_float4(tanf(0.25f*ty), sinf(0.5f*ty), tanf(0.5f*tz), sinf(tz));
  }
}

__global__ __launch_bounds__(BLK, 5) void qsim_kernel(const float* __restrict__ x,
                                                      const float4* __restrict__ gw,
                                                      float* __restrict__ out)
{
  __shared__ f2 st2[DIM];              // exactly 32768 B
  char* lds = (char*)st2;
  const int tid = threadIdx.x;
  const int bb  = blockIdx.x;

  u32 msk[8];
#pragma unroll
  for(int k=0;k<8;++k) msk[k]=0u-((u32)(tid>>k)&1u);

  // ---- step 0: masks are bits 0..3 -> coset = 16 consecutive floats in global ----
  u32 rep0=0, acc0=0;
#pragma unroll
  for(int k=0;k<8;++k){ rep0 ^= DV.g0lane[k]&msk[k]; acc0 ^= DV.lane_c[0][k]&msk[k]; }
  const u32 base0 = acc0 & 0x0FFFFFFFu;   // nib == 0 at step 0

  f2 a[16];
  const float* xr = x + (size_t)bb*DIM + rep0;
#pragma unroll
  for(int s=0;s<4;++s){
    const float4 v = *reinterpret_cast<const float4*>(xr + 4*s);
    a[4*s+0]=(f2){v.x,0.f}; a[4*s+1]=(f2){v.y,0.f};
    a[4*s+2]=(f2){v.z,0.f}; a[4*s+3]=(f2){v.w,0.f};
  }
  gates<0,true>(a,gw);
#pragma unroll
  for(int c=0;c<16;++c){ *(f2*)(lds + (base0 ^ DV.scmb[0][c])) = a[c]; }
  __syncthreads();

  // ---- steps 1..10: LDS round trips ----
  mid_step<1,true >(msk,lds,gw);
  mid_step<2,true >(msk,lds,gw);
  mid_step<3,true >(msk,lds,gw);
  mid_step<4,true >(msk,lds,gw);
  mid_step<5,true >(msk,lds,gw);
  mid_step<6,true >(msk,lds,gw);
  mid_step<7,true >(msk,lds,gw);
  mid_step<8,true >(msk,lds,gw);
  mid_step<9,false>(msk,lds,gw);     // last layer: RZ phase dropped (|amp|^2 readout)
  mid_step<10,false>(msk,lds,gw);

  // ---- step 11 + fused Walsh readout (no write-back) ----
  {
    u32 acc=0, urep=0;
#pragma unroll
    for(int k=0;k<8;++k){ acc ^= DV.lane_c[11][k]&msk[k]; urep ^= DV.u11lane[k]&msk[k]; }
    const u32 nib = acc>>28;
    u32 base = acc & 0x0FFFFFFFu;
#pragma unroll
    for(int i=0;i<4;++i){ const u32 mi=0u-((nib>>i)&1u); base ^= DV.smb[11][i]&mi; urep ^= DV.u11smb[i]&mi; }
#pragma unroll
    for(int c=0;c<16;++c){
      a[c] = *(const f2*)(lds + (base ^ DV.scmb[11][c]));
    }
    gates<11,false>(a,gw);

    float pr[16];
#pragma unroll
    for(int c=0;c<16;++c) pr[c]=fmaf(a[c].x,a[c].x, a[c].y*a[c].y);
    // Walsh-Hadamard over the 4 combo bits: W[m] = sum_c (-1)^{popc(c&m)} pr[c]
#pragma unroll
    for(int b=1;b<16;b<<=1){
#pragma unroll
      for(int c=0;c<16;++c){
        if(c&b) continue;
        const float u=pr[c], v=pr[c|b];
        pr[c]=u+v; pr[c|b]=u-v;
      }
    }
    float accq[12];
#pragma unroll
    for(int q=0;q<12;++q){
      const u32 sb = ((u32)__popc(urep & (u32)DV.pm[q]) & 1u)<<31;
      accq[q]=__uint_as_float(__float_as_uint(pr[DV.mu[q]])^sb);
    }
    float nrm2 = pr[0];
#pragma unroll
    for(int o=32;o;o>>=1){
      nrm2 += __shfl_xor(nrm2,o);
#pragma unroll
      for(int q=0;q<12;++q) accq[q]+=__shfl_xor(accq[q],o);
    }
    __syncthreads();                      // all waves done reading step 11
    float* wredf = (float*)lds;           // alias reduction buffer into state LDS
    const int wid=tid>>6;
    if((tid&63)==0){
#pragma unroll
      for(int q=0;q<12;++q) wredf[wid*13+q]=accq[q];
      wredf[wid*13+12]=nrm2;
    }
    __syncthreads();
    if(tid<NQ){
      const float s0=wredf[0*13+tid]+wredf[1*13+tid]+wredf[2*13+tid]+wredf[3*13+tid];
      const float sn=wredf[0*13+12]+wredf[1*13+12]+wredf[2*13+12]+wredf[3*13+12];
      out[(size_t)bb*NQ+tid]=s0/sn;
    }
  }
}

extern "C" void kernel_launch(void* const* d_in, const int* in_sizes, int n_in,
                              void* d_out, int out_size, void* d_ws, size_t ws_size,
                              hipStream_t stream) {
  const float* x = (const float*)d_in[0];
  const float* w = (const float*)d_in[1];
  float* out = (float*)d_out;
  float4* gw = (float4*)d_ws;
  const int B = in_sizes[0] / DIM;
  prep_kernel<<<1, 64, 0, stream>>>(w, gw);
  qsim_kernel<<<B, BLK, 0, stream>>>(x, gw, out);
}